// Round 1
// baseline (74.869 us; speedup 1.0000x reference)
//
#include <hip/hip_runtime.h>

#define PATCH   16
#define BD      4
#define CD      3
#define HD      512
#define WD      512
#define NPAT    4096
#define TOTAL_ELEMS (4.0 * 3.0 * 4096.0 * 256.0)   // 12,582,912

__global__ __launch_bounds__(256) void patch_loss_kernel(
    const float* __restrict__ fuse,
    const float* __restrict__ img1,
    const float* __restrict__ img2,
    const int*   __restrict__ coords,
    float*       __restrict__ out)
{
    const int lane = threadIdx.x & 63;
    const int wave = threadIdx.x >> 6;
    const int p = blockIdx.x * 4 + wave;   // patch id 0..16383
    const int b = p >> 12;                 // / 4096
    const int n = p & 4095;

    const int h = coords[(b * NPAT + n) * 2 + 0];
    const int w = coords[(b * NPAT + n) * 2 + 1];

    float acc = 0.f;

    #pragma unroll
    for (int c = 0; c < CD; ++c) {
        const size_t base = ((size_t)((b * CD + c) * HD + h)) * WD + w;

        float pf[4], p1[4], p2[4];
        float s1 = 0.f, q1 = 0.f, s2 = 0.f, q2 = 0.f;

        #pragma unroll
        for (int j = 0; j < 4; ++j) {
            const int e   = lane + 64 * j;     // 0..255
            const int r   = e >> 4;            // patch row
            const int col = e & 15;            // patch col
            const size_t idx = base + (size_t)r * WD + col;
            pf[j] = fuse[idx];
            p1[j] = img1[idx];
            p2[j] = img2[idx];
            s1 += p1[j];  q1 += p1[j] * p1[j];
            s2 += p2[j];  q2 += p2[j] * p2[j];
        }

        // Wave-wide (64-lane) butterfly reduction of the 4 statistics.
        #pragma unroll
        for (int off = 32; off >= 1; off >>= 1) {
            s1 += __shfl_xor(s1, off, 64);
            q1 += __shfl_xor(q1, off, 64);
            s2 += __shfl_xor(s2, off, 64);
            q2 += __shfl_xor(q2, off, 64);
        }

        const float inv = 1.f / 256.f;
        const float mu1 = s1 * inv;
        const float mu2 = s2 * inv;
        const float v1  = fmaxf(q1 * inv - mu1 * mu1, 0.f);
        const float v2  = fmaxf(q2 * inv - mu2 * mu2, 0.f);
        const float sd1 = sqrtf(v1);
        const float sd2 = sqrtf(v2);
        const float denom = sd1 + sd2 + 1e-6f;
        const float w1 = sd1 / denom;
        const float w2 = sd2 / denom;

        #pragma unroll
        for (int j = 0; j < 4; ++j) {
            const float t = w1 * p1[j] + w2 * p2[j];
            acc += fabsf(pf[j] - t);
        }
    }

    // Reduce |diff| accumulator across the wave.
    #pragma unroll
    for (int off = 32; off >= 1; off >>= 1)
        acc += __shfl_xor(acc, off, 64);

    __shared__ float partial[4];
    if (lane == 0) partial[wave] = acc;
    __syncthreads();
    if (threadIdx.x == 0) {
        const float s = partial[0] + partial[1] + partial[2] + partial[3];
        atomicAdd(out, s * (float)(1.0 / TOTAL_ELEMS));
    }
}

extern "C" void kernel_launch(void* const* d_in, const int* in_sizes, int n_in,
                              void* d_out, int out_size, void* d_ws, size_t ws_size,
                              hipStream_t stream) {
    const float* fuse   = (const float*)d_in[0];
    const float* img1   = (const float*)d_in[1];
    const float* img2   = (const float*)d_in[2];
    const int*   coords = (const int*)d_in[3];
    float* out = (float*)d_out;

    // d_out is poisoned by the harness; zero the scalar accumulator first.
    hipMemsetAsync(out, 0, sizeof(float), stream);

    const int nPatches = BD * NPAT;          // 16384
    const int blocks   = nPatches / 4;       // 4 waves (patches) per block
    patch_loss_kernel<<<blocks, 256, 0, stream>>>(fuse, img1, img2, coords, out);
}

// Round 2
// 55.798 us; speedup vs baseline: 1.3418x; 1.3418x over previous
//
#include <hip/hip_runtime.h>

#define NPAT 4096
#define TOTAL_ELEMS (4.0 * 3.0 * 4096.0 * 256.0)   // 12,582,912
#define NWAVES (16384 * 3)                          // one wave per (patch, channel)
#define NBLOCKS (NWAVES / 4)                        // 12288

// 16B vector with only 4B alignment guarantee (w coordinate is arbitrary).
typedef float f4 __attribute__((ext_vector_type(4), aligned(4)));

__global__ __launch_bounds__(256) void patch_stage1(
    const float* __restrict__ fuse,
    const float* __restrict__ img1,
    const float* __restrict__ img2,
    const int*   __restrict__ coords,
    float*       __restrict__ partials)
{
    const int lane = threadIdx.x & 63;
    const int wave = threadIdx.x >> 6;
    const int gw = blockIdx.x * 4 + wave;   // 0..49151, channel-fastest
    const int p  = gw / 3;                  // patch id 0..16383
    const int c  = gw - p * 3;              // channel 0..2
    const int b  = p >> 12;
    const int n  = p & 4095;

    const int h = coords[(b * NPAT + n) * 2 + 0];
    const int w = coords[(b * NPAT + n) * 2 + 1];

    // lane covers 4 contiguous elements: row = lane>>2, col = (lane&3)*4
    const size_t base = ((size_t)((b * 3 + c) * 512 + h)) * 512 + w
                      + (size_t)(lane >> 2) * 512 + (size_t)((lane & 3) * 4);

    // Issue all three 16B loads before any dependent compute.
    const f4 vf = *(const f4*)(fuse + base);
    const f4 v1 = *(const f4*)(img1 + base);
    const f4 v2 = *(const f4*)(img2 + base);

    float s1 = v1.x + v1.y + v1.z + v1.w;
    float q1 = v1.x * v1.x + v1.y * v1.y + v1.z * v1.z + v1.w * v1.w;
    float s2 = v2.x + v2.y + v2.z + v2.w;
    float q2 = v2.x * v2.x + v2.y * v2.y + v2.z * v2.z + v2.w * v2.w;

    #pragma unroll
    for (int off = 32; off >= 1; off >>= 1) {
        s1 += __shfl_xor(s1, off, 64);
        q1 += __shfl_xor(q1, off, 64);
        s2 += __shfl_xor(s2, off, 64);
        q2 += __shfl_xor(q2, off, 64);
    }

    const float inv = 1.f / 256.f;
    const float mu1 = s1 * inv;
    const float mu2 = s2 * inv;
    const float sd1 = sqrtf(fmaxf(q1 * inv - mu1 * mu1, 0.f));
    const float sd2 = sqrtf(fmaxf(q2 * inv - mu2 * mu2, 0.f));
    const float denom = sd1 + sd2 + 1e-6f;
    const float w1 = sd1 / denom;
    const float w2 = sd2 / denom;

    float acc = fabsf(vf.x - (w1 * v1.x + w2 * v2.x))
              + fabsf(vf.y - (w1 * v1.y + w2 * v2.y))
              + fabsf(vf.z - (w1 * v1.z + w2 * v2.z))
              + fabsf(vf.w - (w1 * v1.w + w2 * v2.w));

    #pragma unroll
    for (int off = 32; off >= 1; off >>= 1)
        acc += __shfl_xor(acc, off, 64);

    __shared__ float part[4];
    if (lane == 0) part[wave] = acc;
    __syncthreads();
    if (threadIdx.x == 0)
        partials[blockIdx.x] = part[0] + part[1] + part[2] + part[3];
}

__global__ __launch_bounds__(256) void patch_stage2(
    const float* __restrict__ partials, float* __restrict__ out)
{
    float s = 0.f;
    for (int i = threadIdx.x; i < NBLOCKS; i += 256)
        s += partials[i];

    #pragma unroll
    for (int off = 32; off >= 1; off >>= 1)
        s += __shfl_xor(s, off, 64);

    __shared__ float part[4];
    const int lane = threadIdx.x & 63;
    const int wave = threadIdx.x >> 6;
    if (lane == 0) part[wave] = s;
    __syncthreads();
    if (threadIdx.x == 0)
        out[0] = (part[0] + part[1] + part[2] + part[3]) * (float)(1.0 / TOTAL_ELEMS);
}

extern "C" void kernel_launch(void* const* d_in, const int* in_sizes, int n_in,
                              void* d_out, int out_size, void* d_ws, size_t ws_size,
                              hipStream_t stream) {
    const float* fuse   = (const float*)d_in[0];
    const float* img1   = (const float*)d_in[1];
    const float* img2   = (const float*)d_in[2];
    const int*   coords = (const int*)d_in[3];
    float* out      = (float*)d_out;
    float* partials = (float*)d_ws;          // NBLOCKS floats = 48 KiB

    patch_stage1<<<NBLOCKS, 256, 0, stream>>>(fuse, img1, img2, coords, partials);
    patch_stage2<<<1, 256, 0, stream>>>(partials, out);
}